// Round 5
// baseline (312.381 us; speedup 1.0000x reference)
//
#include <hip/hip_runtime.h>
#include <hip/hip_bf16.h>

typedef __attribute__((ext_vector_type(4))) int int4v;

#define TOKENS 8192
#define IN_F   4096
#define OUT_F  4096

// ws layout (bytes):
//   0     : double hdr[2]  (hdr[0]=mean, hdr[1]=scale)
//   1024  : double partials[1024]      (weight sums)
//   9216  : float  xpart[1024]         (per-block |x| max)
//   16384 : int8 q[TOKENS][IN_F]
//   16384 + TOKENS*IN_F: int8 s[OUT_F][IN_F]

// fused pre-pass: blocks [0,1024) sum one weight row-block each;
// blocks [1024,2048) grid-stride max over |x|.
__global__ __launch_bounds__(256) void k_pre(const float4* __restrict__ w,
                                             const float4* __restrict__ x,
                                             double* __restrict__ partials,
                                             float* __restrict__ xpart) {
  if (blockIdx.x < 1024) {
    __shared__ double sm[256];
    double s = 0.0;
    const float4* p = w + (size_t)blockIdx.x * 4096;
    for (int i = threadIdx.x; i < 4096; i += 256) {
      float4 v = p[i];
      s += (double)v.x + (double)v.y + (double)v.z + (double)v.w;
    }
    sm[threadIdx.x] = s;
    __syncthreads();
    for (int off = 128; off > 0; off >>= 1) {
      if (threadIdx.x < off) sm[threadIdx.x] += sm[threadIdx.x + off];
      __syncthreads();
    }
    if (threadIdx.x == 0) partials[blockIdx.x] = sm[0];
  } else {
    const int b = blockIdx.x - 1024;
    float m = 0.f;
    const size_t n = (size_t)TOKENS * IN_F / 4;
    for (size_t i = (size_t)b * 256 + threadIdx.x; i < n; i += (size_t)1024 * 256) {
      float4 v = x[i];
      m = fmaxf(m, fmaxf(fmaxf(fabsf(v.x), fabsf(v.y)),
                         fmaxf(fabsf(v.z), fabsf(v.w))));
    }
    __shared__ float smf[256];
    smf[threadIdx.x] = m;
    __syncthreads();
    for (int off = 128; off > 0; off >>= 1) {
      if (threadIdx.x < off) smf[threadIdx.x] = fmaxf(smf[threadIdx.x], smf[threadIdx.x + off]);
      __syncthreads();
    }
    if (threadIdx.x == 0) xpart[b] = smf[0];
  }
}

__global__ __launch_bounds__(256) void k_finalize(double* __restrict__ hdr,
                                                  const double* __restrict__ partials,
                                                  const float* __restrict__ xpart) {
  __shared__ double sm[256];
  __shared__ float smf[256];
  double s = partials[threadIdx.x] + partials[threadIdx.x + 256] +
             partials[threadIdx.x + 512] + partials[threadIdx.x + 768];
  float m = fmaxf(fmaxf(xpart[threadIdx.x], xpart[threadIdx.x + 256]),
                  fmaxf(xpart[threadIdx.x + 512], xpart[threadIdx.x + 768]));
  sm[threadIdx.x] = s;
  smf[threadIdx.x] = m;
  __syncthreads();
  for (int off = 128; off > 0; off >>= 1) {
    if (threadIdx.x < off) {
      sm[threadIdx.x] += sm[threadIdx.x + off];
      smf[threadIdx.x] = fmaxf(smf[threadIdx.x], smf[threadIdx.x + off]);
    }
    __syncthreads();
  }
  if (threadIdx.x == 0) {
    hdr[0] = sm[0] / (double)((size_t)OUT_F * IN_F);   // mean of weight
    hdr[1] = 127.0 / (double)smf[0];                   // absmax scale
  }
}

// fused: blocks [0, QB_BLK) quantize x; blocks [QB_BLK, QB_BLK+TB_BLK) ternarize w
#define QB_BLK ((TOKENS * IN_F / 4) / 256)
#define TB_BLK ((OUT_F * IN_F / 4) / 256)
__global__ __launch_bounds__(256) void k_quant_tern(const float4* __restrict__ x,
                                                    const float4* __restrict__ w,
                                                    int* __restrict__ q,
                                                    int* __restrict__ sgn,
                                                    const double* __restrict__ hdr) {
  if (blockIdx.x < QB_BLK) {
    const double s = hdr[1];
    size_t i = (size_t)blockIdx.x * 256 + threadIdx.x;
    float4 v = x[i];
    int a = (int)rint(s * (double)v.x);
    int b = (int)rint(s * (double)v.y);
    int c = (int)rint(s * (double)v.z);
    int d = (int)rint(s * (double)v.w);
    q[i] = (a & 255) | ((b & 255) << 8) | ((c & 255) << 16) | ((d & 255) << 24);
  } else {
    const double m = hdr[0];
    size_t i = (size_t)(blockIdx.x - QB_BLK) * 256 + threadIdx.x;
    float4 v = w[i];
    int a = ((double)v.x > m) - ((double)v.x < m);
    int b = ((double)v.y > m) - ((double)v.y < m);
    int c = ((double)v.z > m) - ((double)v.z < m);
    int d = ((double)v.w > m) - ((double)v.w < m);
    sgn[i] = (a & 255) | ((b & 255) << 8) | ((c & 255) << 16) | ((d & 255) << 24);
  }
}

// ---------------------------------------------------------------------------
// int8 GEMM, 256x256 tile, BK=64B. A: 3-deep LDS ring (48KB), staged 2 tiles
// ahead via global_load_lds, XOR-swizzled source / linear dest (rule #21).
// B: DIRECT global->VGPR fragment loads from row-major sbuf (no LDS) —
// each wave-load touches 16 distinct 64B lines, all bytes consumed (the 4
// same-row lanes split each line), so it's as line-efficient as contiguous.
// B register double-buffer, distance-1 prefetch (~1 iter ≈ 1300cyc of cover).
// Issue order per iter: [b(kt+1) x4][stageA(kt+2) x2] -> vmcnt(2) at bottom
// lands b(kt+1)+A(kt+1), keeps A(kt+2) in flight (never drains to 0).
// 8 waves 2M x 4N, per-wave 128x64 out, 32 independent MFMAs/K-tile.
// LDS/K-tile: 64KB read + 16KB write = ~714cyc << 1306cyc MFMA floor.
// ---------------------------------------------------------------------------
__device__ __forceinline__ void stageA(const signed char* __restrict__ gsrc,
                                       size_t grow0, int ktile,
                                       signed char* ldsbase, int tid, int wid) {
#pragma unroll
  for (int i = 0; i < 2; ++i) {
    const int slot = i * 512 + tid;
    const int r = slot >> 2;            // row 0..255
    const int sir = slot & 3;           // stored 16B position in row
    const signed char* g = gsrc + (grow0 + (size_t)r) * IN_F +
                           (size_t)ktile * 64 + ((sir ^ ((r >> 1) & 3)) << 4);
    __builtin_amdgcn_global_load_lds(
        (const __attribute__((address_space(1))) void*)g,
        (__attribute__((address_space(3))) void*)(ldsbase + (i * 512 + wid * 64) * 16),
        16, 0, 0);
  }
}

__global__ __launch_bounds__(512, 2) void k_gemm(const signed char* __restrict__ q,
                                                 const signed char* __restrict__ s,
                                                 float* __restrict__ out) {
  __shared__ signed char sA[3][256 * 64];   // 48 KB
  const int tid  = threadIdx.x;
  const int lane = tid & 63;
  const int wid  = tid >> 6;     // 0..7
  const int wm   = wid >> 2;     // 0..1 -> row offset wm*128
  const int wn   = wid & 3;      // 0..3 -> col offset wn*64
  const int l15  = lane & 15, l4 = lane >> 4;

  // XCD-aware swizzle: 512 blocks, 8 XCDs, 64 blocks/XCD chunk (bijective)
  const int swz = (blockIdx.x & 7) * 64 + (blockIdx.x >> 3);
  const int bm = swz >> 4;       // 0..31  (M tiles of 256)
  const int bn = swz & 15;       // 0..15  (N tiles of 256)
  const size_t row0 = (size_t)bm * 256;
  const size_t col0 = (size_t)bn * 256;

  // A ds_read swizzle (matches stageA source XOR; verified 0-conflict)
  const int lane_off = l15 * 64 + ((l4 ^ ((l15 >> 1) & 3)) << 4);

  // B per-lane fragment base: row (col0+wn*64+l15), k-offset l4*16
  const signed char* bptr = s + (col0 + (size_t)(wn * 64 + l15)) * IN_F + l4 * 16;

  int4v acc[8][4];
#pragma unroll
  for (int i = 0; i < 8; ++i)
#pragma unroll
    for (int j = 0; j < 4; ++j) acc[i][j] = int4v{0, 0, 0, 0};

  int4v bc[4], bnx[4];

  // prologue: [stage A0 x2][b0 x4][stage A1 x2] -> vmcnt(2) lands A0+b0
  stageA(q, row0, 0, sA[0], tid, wid);
  __builtin_amdgcn_sched_barrier(0);
#pragma unroll
  for (int f = 0; f < 4; ++f)
    bnx[f] = *(const int4v*)(bptr + (size_t)f * 16 * IN_F);
  __builtin_amdgcn_sched_barrier(0);
  stageA(q, row0, 1, sA[1], tid, wid);
  __builtin_amdgcn_sched_barrier(0);
  asm volatile("s_waitcnt vmcnt(2)" ::: "memory");
  __builtin_amdgcn_sched_barrier(0);
  __builtin_amdgcn_s_barrier();
  __builtin_amdgcn_sched_barrier(0);
#pragma unroll
  for (int f = 0; f < 4; ++f) bc[f] = bnx[f];

  int cur = 0, stg = 2;
  for (int kt = 0; kt < 64; ++kt) {
    const signed char* bufA = sA[cur];

    // b(kt+1) loads FIRST (vmcnt ordering), then stage A(kt+2)
    const int bt = (kt + 1) & 63;
#pragma unroll
    for (int f = 0; f < 4; ++f)
      bnx[f] = *(const int4v*)(bptr + (size_t)f * 16 * IN_F + bt * 64);
    __builtin_amdgcn_sched_barrier(0);
    stageA(q, row0, (kt + 2) & 63, sA[stg], tid, wid);
    __builtin_amdgcn_sched_barrier(0);

    // a-reads for this tile
    int4v a[8];
#pragma unroll
    for (int m = 0; m < 8; ++m)
      a[m] = *(const int4v*)(bufA + (wm * 128 + m * 16) * 64 + lane_off);
    asm volatile("s_waitcnt lgkmcnt(0)" ::: "memory");
    __builtin_amdgcn_sched_barrier(0);
    __builtin_amdgcn_s_setprio(1);
#pragma unroll
    for (int m = 0; m < 8; ++m)
#pragma unroll
      for (int n = 0; n < 4; ++n)
        acc[m][n] = __builtin_amdgcn_mfma_i32_16x16x64_i8(a[m], bc[n], acc[m][n], 0, 0, 0);
    __builtin_amdgcn_s_setprio(0);
    __builtin_amdgcn_sched_barrier(0);
    // land b(kt+1) + A(kt+1); keep A(kt+2)'s 2 loads in flight
    asm volatile("s_waitcnt vmcnt(2)" ::: "memory");
    __builtin_amdgcn_sched_barrier(0);
    __builtin_amdgcn_s_barrier();
    __builtin_amdgcn_sched_barrier(0);
#pragma unroll
    for (int f = 0; f < 4; ++f) bc[f] = bnx[f];

    cur = (cur == 2) ? 0 : cur + 1;
    stg = (stg == 2) ? 0 : stg + 1;
  }

  // epilogue: C/D mapping col = lane&15, row = (lane>>4)*4 + r
#pragma unroll
  for (int m = 0; m < 8; ++m)
#pragma unroll
    for (int n = 0; n < 4; ++n)
#pragma unroll
      for (int r = 0; r < 4; ++r) {
        const size_t rg = row0 + wm * 128 + m * 16 + l4 * 4 + r;
        const size_t cg = col0 + wn * 64 + n * 16 + l15;
        out[rg * OUT_F + cg] = (float)acc[m][n][r];
      }
}

extern "C" void kernel_launch(void* const* d_in, const int* in_sizes, int n_in,
                              void* d_out, int out_size, void* d_ws, size_t ws_size,
                              hipStream_t stream) {
  const float* x = (const float*)d_in[0];   // input  [8192][4096] f32
  const float* w = (const float*)d_in[1];   // weight [4096][4096] f32
  float* out = (float*)d_out;               // [8192][4096] f32

  char* ws = (char*)d_ws;
  double*   hdr      = (double*)ws;
  double*   partials = (double*)(ws + 1024);
  float*    xpart    = (float*)(ws + 9216);
  signed char* qbuf  = (signed char*)(ws + 16384);
  signed char* sbuf  = (signed char*)(ws + 16384 + (size_t)TOKENS * IN_F);

  k_pre<<<2048, 256, 0, stream>>>((const float4*)w, (const float4*)x, partials, xpart);
  k_finalize<<<1, 256, 0, stream>>>(hdr, partials, xpart);
  k_quant_tern<<<QB_BLK + TB_BLK, 256, 0, stream>>>((const float4*)x, (const float4*)w,
                                                    (int*)qbuf, (int*)sbuf, hdr);
  k_gemm<<<(TOKENS / 256) * (OUT_F / 256), 512, 0, stream>>>(qbuf, sbuf, out);
}

// Round 6
// 235.859 us; speedup vs baseline: 1.3244x; 1.3244x over previous
//
#include <hip/hip_runtime.h>
#include <hip/hip_bf16.h>

typedef __attribute__((ext_vector_type(4))) int int4v;

#define TOKENS 8192
#define IN_F   4096
#define OUT_F  4096

// ws layout (bytes):
//   0     : double hdr[2]  (hdr[0]=mean, hdr[1]=scale)
//   1024  : double partials[1024]      (weight sums)
//   9216  : float  xpart[1024]         (per-block |x| max)
//   16384 : int8 q[TOKENS][IN_F]
//   16384 + TOKENS*IN_F: int8 s[OUT_F][IN_F]

__global__ __launch_bounds__(256) void k_pre(const float4* __restrict__ w,
                                             const float4* __restrict__ x,
                                             double* __restrict__ partials,
                                             float* __restrict__ xpart) {
  if (blockIdx.x < 1024) {
    __shared__ double sm[256];
    double s = 0.0;
    const float4* p = w + (size_t)blockIdx.x * 4096;
    for (int i = threadIdx.x; i < 4096; i += 256) {
      float4 v = p[i];
      s += (double)v.x + (double)v.y + (double)v.z + (double)v.w;
    }
    sm[threadIdx.x] = s;
    __syncthreads();
    for (int off = 128; off > 0; off >>= 1) {
      if (threadIdx.x < off) sm[threadIdx.x] += sm[threadIdx.x + off];
      __syncthreads();
    }
    if (threadIdx.x == 0) partials[blockIdx.x] = sm[0];
  } else {
    const int b = blockIdx.x - 1024;
    float m = 0.f;
    const size_t n = (size_t)TOKENS * IN_F / 4;
    for (size_t i = (size_t)b * 256 + threadIdx.x; i < n; i += (size_t)1024 * 256) {
      float4 v = x[i];
      m = fmaxf(m, fmaxf(fmaxf(fabsf(v.x), fabsf(v.y)),
                         fmaxf(fabsf(v.z), fabsf(v.w))));
    }
    __shared__ float smf[256];
    smf[threadIdx.x] = m;
    __syncthreads();
    for (int off = 128; off > 0; off >>= 1) {
      if (threadIdx.x < off) smf[threadIdx.x] = fmaxf(smf[threadIdx.x], smf[threadIdx.x + off]);
      __syncthreads();
    }
    if (threadIdx.x == 0) xpart[b] = smf[0];
  }
}

__global__ __launch_bounds__(256) void k_finalize(double* __restrict__ hdr,
                                                  const double* __restrict__ partials,
                                                  const float* __restrict__ xpart) {
  __shared__ double sm[256];
  __shared__ float smf[256];
  double s = partials[threadIdx.x] + partials[threadIdx.x + 256] +
             partials[threadIdx.x + 512] + partials[threadIdx.x + 768];
  float m = fmaxf(fmaxf(xpart[threadIdx.x], xpart[threadIdx.x + 256]),
                  fmaxf(xpart[threadIdx.x + 512], xpart[threadIdx.x + 768]));
  sm[threadIdx.x] = s;
  smf[threadIdx.x] = m;
  __syncthreads();
  for (int off = 128; off > 0; off >>= 1) {
    if (threadIdx.x < off) {
      sm[threadIdx.x] += sm[threadIdx.x + off];
      smf[threadIdx.x] = fmaxf(smf[threadIdx.x], smf[threadIdx.x + off]);
    }
    __syncthreads();
  }
  if (threadIdx.x == 0) {
    hdr[0] = sm[0] / (double)((size_t)OUT_F * IN_F);   // mean of weight
    hdr[1] = 127.0 / (double)smf[0];                   // absmax scale
  }
}

#define QB_BLK ((TOKENS * IN_F / 4) / 256)
#define TB_BLK ((OUT_F * IN_F / 4) / 256)
__global__ __launch_bounds__(256) void k_quant_tern(const float4* __restrict__ x,
                                                    const float4* __restrict__ w,
                                                    int* __restrict__ q,
                                                    int* __restrict__ sgn,
                                                    const double* __restrict__ hdr) {
  if (blockIdx.x < QB_BLK) {
    const double s = hdr[1];
    size_t i = (size_t)blockIdx.x * 256 + threadIdx.x;
    float4 v = x[i];
    int a = (int)rint(s * (double)v.x);
    int b = (int)rint(s * (double)v.y);
    int c = (int)rint(s * (double)v.z);
    int d = (int)rint(s * (double)v.w);
    q[i] = (a & 255) | ((b & 255) << 8) | ((c & 255) << 16) | ((d & 255) << 24);
  } else {
    const double m = hdr[0];
    size_t i = (size_t)(blockIdx.x - QB_BLK) * 256 + threadIdx.x;
    float4 v = w[i];
    int a = ((double)v.x > m) - ((double)v.x < m);
    int b = ((double)v.y > m) - ((double)v.y < m);
    int c = ((double)v.z > m) - ((double)v.z < m);
    int d = ((double)v.w > m) - ((double)v.w < m);
    sgn[i] = (a & 255) | ((b & 255) << 8) | ((c & 255) << 16) | ((d & 255) << 24);
  }
}

// ---------------------------------------------------------------------------
// int8 GEMM, 256x256 tile, BK=64B, 4-deep LDS ring, vmcnt(8) never-drain,
// XOR-swizzled LDS (0-conflict, verified R3), XCD swizzle. NEW vs R3: the
// K-tile is split into FOUR balanced phases (8 MFMA each) instead of two
// (16+16 with 10/2 ds_read split) so ds_read / stage / MFMA interleave per
// m196/m201. Each phase: {reads + 1 stage-unit; barrier; lgkm(0); setprio;
// 8 MFMA; barrier}. vmcnt(8) sits in phase 3 (stage of kt+3 just issued,
// waits tile kt+1 = 4 oldest of 12 outstanding). Ring-lifetime proof as R3.
// ---------------------------------------------------------------------------
__device__ __forceinline__ void stage_unit(const signed char* __restrict__ gsrc,
                                           size_t grow0, int ktile,
                                           signed char* ldsbase, int tid, int wid,
                                           int half) {
  const int slot = half * 512 + tid;
  const int r = slot >> 2;            // row 0..255
  const int sir = slot & 3;           // stored 16B position in row
  const signed char* g = gsrc + (grow0 + (size_t)r) * IN_F +
                         (size_t)ktile * 64 + ((sir ^ ((r >> 1) & 3)) << 4);
  __builtin_amdgcn_global_load_lds(
      (const __attribute__((address_space(1))) void*)g,
      (__attribute__((address_space(3))) void*)(ldsbase + (half * 512 + wid * 64) * 16),
      16, 0, 0);
}

#define PHASE_SYNC_PRE()                                   \
  __builtin_amdgcn_sched_barrier(0);                       \
  __builtin_amdgcn_s_barrier();                            \
  asm volatile("s_waitcnt lgkmcnt(0)" ::: "memory");       \
  __builtin_amdgcn_sched_barrier(0);                       \
  __builtin_amdgcn_s_setprio(1)

#define PHASE_SYNC_POST()                                  \
  __builtin_amdgcn_s_setprio(0);                           \
  __builtin_amdgcn_sched_barrier(0);                       \
  __builtin_amdgcn_s_barrier()

__global__ __launch_bounds__(512, 2) void k_gemm(const signed char* __restrict__ q,
                                                 const signed char* __restrict__ s,
                                                 float* __restrict__ out) {
  __shared__ signed char sA[4][256 * 64];   // 64 KB
  __shared__ signed char sB[4][256 * 64];   // 64 KB
  const int tid  = threadIdx.x;
  const int lane = tid & 63;
  const int wid  = tid >> 6;     // 0..7
  const int wm   = wid >> 2;     // 0..1 -> row offset wm*128
  const int wn   = wid & 3;      // 0..3 -> col offset wn*64
  const int l15  = lane & 15, l4 = lane >> 4;

  // XCD-aware swizzle: 512 blocks, 8 XCDs, 64 blocks/XCD chunk (bijective)
  const int swz = (blockIdx.x & 7) * 64 + (blockIdx.x >> 3);
  const int bm = swz >> 4;       // 0..31
  const int bn = swz & 15;       // 0..15
  const size_t row0 = (size_t)bm * 256;
  const size_t col0 = (size_t)bn * 256;

  const int lane_off = l15 * 64 + ((l4 ^ ((l15 >> 1) & 3)) << 4);

  int4v acc[8][4];
#pragma unroll
  for (int i = 0; i < 8; ++i)
#pragma unroll
    for (int j = 0; j < 4; ++j) acc[i][j] = int4v{0, 0, 0, 0};

  // prologue: stage tiles 0,1,2 into bufs 0,1,2 (12 gloads)
#pragma unroll
  for (int t = 0; t < 3; ++t) {
    stage_unit(q, row0, t, sA[t], tid, wid, 0);
    stage_unit(q, row0, t, sA[t], tid, wid, 1);
    stage_unit(s, col0, t, sB[t], tid, wid, 0);
    stage_unit(s, col0, t, sB[t], tid, wid, 1);
  }
  asm volatile("s_waitcnt vmcnt(8)" ::: "memory");   // tile 0 (oldest 4) landed
  __builtin_amdgcn_sched_barrier(0);
  __builtin_amdgcn_s_barrier();
  __builtin_amdgcn_sched_barrier(0);

  for (int kt = 0; kt < 64; ++kt) {
    const int c = kt & 3;
    const int pf   = (kt + 3) & 63;
    const int pbuf = (kt + 3) & 3;
    const signed char* bufA = sA[c];
    const signed char* bufB = sB[c];

    int4v a[8], b[4];

    // ---- phase 0: read a[0..3], b[0..1]; stage A-half0; MFMA m0-3 x n0-1 ----
#pragma unroll
    for (int m = 0; m < 4; ++m)
      a[m] = *(const int4v*)(bufA + (wm * 128 + m * 16) * 64 + lane_off);
    b[0] = *(const int4v*)(bufB + (wn * 64 + 0) * 64 + lane_off);
    b[1] = *(const int4v*)(bufB + (wn * 64 + 16) * 64 + lane_off);
    stage_unit(q, row0, pf, sA[pbuf], tid, wid, 0);
    PHASE_SYNC_PRE();
#pragma unroll
    for (int m = 0; m < 4; ++m) {
      acc[m][0] = __builtin_amdgcn_mfma_i32_16x16x64_i8(a[m], b[0], acc[m][0], 0, 0, 0);
      acc[m][1] = __builtin_amdgcn_mfma_i32_16x16x64_i8(a[m], b[1], acc[m][1], 0, 0, 0);
    }
    PHASE_SYNC_POST();

    // ---- phase 1: read a[4..7]; stage A-half1; MFMA m4-7 x n0-1 ----
#pragma unroll
    for (int m = 4; m < 8; ++m)
      a[m] = *(const int4v*)(bufA + (wm * 128 + m * 16) * 64 + lane_off);
    stage_unit(q, row0, pf, sA[pbuf], tid, wid, 1);
    PHASE_SYNC_PRE();
#pragma unroll
    for (int m = 4; m < 8; ++m) {
      acc[m][0] = __builtin_amdgcn_mfma_i32_16x16x64_i8(a[m], b[0], acc[m][0], 0, 0, 0);
      acc[m][1] = __builtin_amdgcn_mfma_i32_16x16x64_i8(a[m], b[1], acc[m][1], 0, 0, 0);
    }
    PHASE_SYNC_POST();

    // ---- phase 2: read b[2..3]; stage B-half0; MFMA m0-3 x n2-3 ----
    b[2] = *(const int4v*)(bufB + (wn * 64 + 32) * 64 + lane_off);
    b[3] = *(const int4v*)(bufB + (wn * 64 + 48) * 64 + lane_off);
    stage_unit(s, col0, pf, sB[pbuf], tid, wid, 0);
    PHASE_SYNC_PRE();
#pragma unroll
    for (int m = 0; m < 4; ++m) {
      acc[m][2] = __builtin_amdgcn_mfma_i32_16x16x64_i8(a[m], b[2], acc[m][2], 0, 0, 0);
      acc[m][3] = __builtin_amdgcn_mfma_i32_16x16x64_i8(a[m], b[3], acc[m][3], 0, 0, 0);
    }
    PHASE_SYNC_POST();

    // ---- phase 3: stage B-half1; vmcnt(8) = tile kt+1 landed; MFMA m4-7 x n2-3 ----
    stage_unit(s, col0, pf, sB[pbuf], tid, wid, 1);
    asm volatile("s_waitcnt vmcnt(8)" ::: "memory");
    __builtin_amdgcn_sched_barrier(0);
    __builtin_amdgcn_s_barrier();
    __builtin_amdgcn_sched_barrier(0);
    __builtin_amdgcn_s_setprio(1);
#pragma unroll
    for (int m = 4; m < 8; ++m) {
      acc[m][2] = __builtin_amdgcn_mfma_i32_16x16x64_i8(a[m], b[2], acc[m][2], 0, 0, 0);
      acc[m][3] = __builtin_amdgcn_mfma_i32_16x16x64_i8(a[m], b[3], acc[m][3], 0, 0, 0);
    }
    PHASE_SYNC_POST();
  }

  // epilogue: C/D mapping col = lane&15, row = (lane>>4)*4 + r
#pragma unroll
  for (int m = 0; m < 8; ++m)
#pragma unroll
    for (int n = 0; n < 4; ++n)
#pragma unroll
      for (int r = 0; r < 4; ++r) {
        const size_t rg = row0 + wm * 128 + m * 16 + l4 * 4 + r;
        const size_t cg = col0 + wn * 64 + n * 16 + l15;
        out[rg * OUT_F + cg] = (float)acc[m][n][r];
      }
}

extern "C" void kernel_launch(void* const* d_in, const int* in_sizes, int n_in,
                              void* d_out, int out_size, void* d_ws, size_t ws_size,
                              hipStream_t stream) {
  const float* x = (const float*)d_in[0];   // input  [8192][4096] f32
  const float* w = (const float*)d_in[1];   // weight [4096][4096] f32
  float* out = (float*)d_out;               // [8192][4096] f32

  char* ws = (char*)d_ws;
  double*   hdr      = (double*)ws;
  double*   partials = (double*)(ws + 1024);
  float*    xpart    = (float*)(ws + 9216);
  signed char* qbuf  = (signed char*)(ws + 16384);
  signed char* sbuf  = (signed char*)(ws + 16384 + (size_t)TOKENS * IN_F);

  k_pre<<<2048, 256, 0, stream>>>((const float4*)w, (const float4*)x, partials, xpart);
  k_finalize<<<1, 256, 0, stream>>>(hdr, partials, xpart);
  k_quant_tern<<<QB_BLK + TB_BLK, 256, 0, stream>>>((const float4*)x, (const float4*)w,
                                                    (int*)qbuf, (int*)sbuf, hdr);
  k_gemm<<<(TOKENS / 256) * (OUT_F / 256), 512, 0, stream>>>(qbuf, sbuf, out);
}